// Round 8
// baseline (164.670 us; speedup 1.0000x reference)
//
#include <hip/hip_runtime.h>

#define N_NODES 100000
#define N_EDGES 1600000
#define D 64
#define NB 782                 // ceil(100000/128) dst-buckets of 128 nodes
#define CAP 3072               // slab slots per bucket (mean 2048, sigma~45)
#define EPB 8192               // edges per partition block
#define NPART ((N_EDGES + EPB - 1) / EPB)   // 196
#define RSH 14                 // src-range shift: range = src>>14 in 0..6

typedef unsigned short ushort_t;
typedef unsigned int uint_t;

// ---------- K1: repack feat -> bf16 (RNE) + init gcur ----------
__device__ __forceinline__ ushort_t f2bf(float f) {
    uint_t u = __float_as_uint(f);
    u += 0x7FFF + ((u >> 16) & 1);          // round-nearest-even
    return (ushort_t)(u >> 16);
}

__global__ __launch_bounds__(256) void repack_init(const float* __restrict__ feat,
                                                   ushort_t* __restrict__ featb,
                                                   int* __restrict__ gcur) {
    const int tid = blockIdx.x * 256 + threadIdx.x;
    if (tid < NB) gcur[tid] = tid * CAP;
    const int base = tid * 16;              // 16 floats per thread
    if (base >= N_NODES * D) return;
    const float4* f4 = (const float4*)(feat + base);
    ushort4* o4 = (ushort4*)(featb + base);
#pragma unroll
    for (int j = 0; j < 4; ++j) {
        const float4 v = f4[j];
        o4[j] = make_ushort4(f2bf(v.x), f2bf(v.y), f2bf(v.z), f2bf(v.w));
    }
}

// ---------- K2: partition edges into per-bucket slabs ----------
__global__ __launch_bounds__(1024) void partition(const int* __restrict__ esrc,
                                                  const int* __restrict__ edst,
                                                  int* __restrict__ gcur,
                                                  int* __restrict__ slab) {
    __shared__ int stage[EPB];              // 32 KB: packed, sorted by bucket
    __shared__ ushort_t bkt16[EPB];         // 16 KB: bucket of sorted pos
    __shared__ int cnt[NB];
    __shared__ int cur[NB];
    __shared__ int gb[NB];
    __shared__ int s[1024];
    const int t = threadIdx.x;
    const int base = blockIdx.x * EPB;
    const int n = min(EPB, N_EDGES - base);

    if (t < NB) cnt[t] = 0;
    __syncthreads();
    for (int i = t; i < n; i += 1024)
        atomicAdd(&cnt[edst[base + i] >> 7], 1);
    __syncthreads();
    const int v = (t < NB) ? cnt[t] : 0;
    s[t] = v;
    __syncthreads();
    for (int off = 1; off < 1024; off <<= 1) {
        const int x = (t >= off) ? s[t - off] : 0;
        __syncthreads();
        s[t] += x;
        __syncthreads();
    }
    if (t < NB) {
        const int excl = s[t] - v;          // exclusive prefix
        cur[t] = excl;
        gb[t] = (v ? atomicAdd(&gcur[t], v) : 0) - excl;
    }
    __syncthreads();
    for (int i = t; i < n; i += 1024) {     // coalesced re-read (L2-hot)
        const int d = edst[base + i];
        const int bkt = d >> 7;
        const int pos = atomicAdd(&cur[bkt], 1);
        stage[pos] = ((d & 127) << 17) | esrc[base + i];
        bkt16[pos] = (ushort_t)bkt;
    }
    __syncthreads();
    for (int i = t; i < n; i += 1024) {     // coalesced segment writes
        const int bkt = bkt16[i];
        const int gp = gb[bkt] + i;
        if (gp < (bkt + 1) * CAP)           // overflow guard (never expected)
            slab[gp] = stage[i];
    }
}

// ---------- 8-lane all-reduce on the VALU pipe (DPP, no DS ops) ----------
template<int CTRL>
__device__ __forceinline__ float fadd_dpp(float x) {
    const int r = __builtin_amdgcn_update_dpp(0, __float_as_int(x), CTRL, 0xF, 0xF, true);
    return x + __int_as_float(r);
}
__device__ __forceinline__ float red8(float p) {
    p = fadd_dpp<0xB1>(p);    // quad_perm [1,0,3,2]  : xor 1
    p = fadd_dpp<0x4E>(p);    // quad_perm [2,3,0,1]  : xor 2
    p = fadd_dpp<0x141>(p);   // row_half_mirror      : xor within 8
    return p;
}

// cvt 8 bf16 (uint4) -> g[8] fp32, and dot vs h[8]
__device__ __forceinline__ float cvt_dot(const uint4 u, const float* __restrict__ h,
                                         float* __restrict__ g) {
    g[0] = __uint_as_float(u.x << 16); g[1] = __uint_as_float(u.x & 0xFFFF0000u);
    g[2] = __uint_as_float(u.y << 16); g[3] = __uint_as_float(u.y & 0xFFFF0000u);
    g[4] = __uint_as_float(u.z << 16); g[5] = __uint_as_float(u.z & 0xFFFF0000u);
    g[6] = __uint_as_float(u.w << 16); g[7] = __uint_as_float(u.w & 0xFFFF0000u);
    float p = 0.f;
#pragma unroll
    for (int k = 0; k < 8; ++k) p += g[k] * h[k];
    return p;
}

// process one quad of gathered rows against h, accumulate into acc
__device__ __forceinline__ void quad_proc(const uint4 u0, const uint4 u1,
                                          const uint4 u2, const uint4 u3,
                                          const float* __restrict__ h,
                                          float* __restrict__ acc) {
    float g0[8], g1[8], g2[8], g3[8];
    float p0 = cvt_dot(u0, h, g0);
    float p1 = cvt_dot(u1, h, g1);
    float p2 = cvt_dot(u2, h, g2);
    float p3 = cvt_dot(u3, h, g3);
    p0 = red8(p0); p1 = red8(p1); p2 = red8(p2); p3 = red8(p3);
#pragma unroll
    for (int k = 0; k < 8; ++k)
        acc[k] += g0[k] * p0 + g1[k] * p1 + g2[k] * p2 + g3[k] * p3;
}

// ---------- K3: fused SDDMM + SpMM ----------
// Round-7 structure, pipeline deepened 2 -> 3: quads q+1 AND q+2 are in
// flight while quad q is processed (12 outstanding 16B gathers/thread).
// Cost: +16 VGPR (~72 expected) -> ~28 waves/CU (was 32); net outstanding
// loads per CU +31%. Tripwire: VGPR > 84 or WRITE > 25.5 MB => revert.
__global__ __launch_bounds__(512) void fused_spmm(const float4* __restrict__ feat4,
                                                  const uint4* __restrict__ featb4,
                                                  const int* __restrict__ slab,
                                                  const int* __restrict__ gcur,
                                                  float4* __restrict__ neigh4) {
    __shared__ int seA[CAP];                // 12 KB: raw packed (slab cache)
    __shared__ int seB[CAP];                // 12 KB: srcs sorted by (dst,rng)
    __shared__ int cnt[1024];
    __shared__ int cur[1024];
    __shared__ int rowoff[129];
    __shared__ int s[512];
    const int t = threadIdx.x;
    const int b = blockIdx.x;
    const int nbase = b << 7;
    const int nb_nodes = min(128, N_NODES - nbase);
    const int sbase = b * CAP;
    const int ne = min(gcur[b] - sbase, CAP);

    for (int i = t; i < ne; i += 512) seA[i] = slab[sbase + i];
    cnt[t] = 0; cnt[t + 512] = 0;
    __syncthreads();
    for (int i = t; i < ne; i += 512) {
        const int pk = seA[i];
        atomicAdd(&cnt[((pk >> 17) << 3) | ((pk & 0x1FFFF) >> RSH)], 1);
    }
    __syncthreads();
    const int v0 = cnt[2 * t], v1 = cnt[2 * t + 1];
    const int sum = v0 + v1;
    s[t] = sum;
    __syncthreads();
    for (int off = 1; off < 512; off <<= 1) {
        const int x = (t >= off) ? s[t - off] : 0;
        __syncthreads();
        s[t] += x;
        __syncthreads();
    }
    const int excl = s[t] - sum;
    cur[2 * t] = excl;
    cur[2 * t + 1] = excl + v0;
    __syncthreads();
    if (t < 128) rowoff[t] = cur[t << 3];
    if (t == 0) rowoff[128] = ne;
    __syncthreads();
    for (int i = t; i < ne; i += 512) {
        const int pk = seA[i];
        const int key = ((pk >> 17) << 3) | ((pk & 0x1FFFF) >> RSH);
        const int pos = atomicAdd(&cur[key], 1);
        seB[pos] = pk & 0x1FFFF;
    }
    __syncthreads();

    const int slot = t >> 3;                // 64 node-slots per block
    const int l = t & 7;                    // lane owns dims 8l..8l+7
#pragma unroll
    for (int ln0 = 0; ln0 < 128; ln0 += 64) {
        const int ln = ln0 + slot;
        if (ln >= nb_nodes) continue;       // no barriers below: safe
        const int nidx = nbase + ln;
        float h[8];
        {
            const float4 ha = feat4[nidx * 16 + 2 * l];
            const float4 hb = feat4[nidx * 16 + 2 * l + 1];
            h[0] = ha.x; h[1] = ha.y; h[2] = ha.z; h[3] = ha.w;
            h[4] = hb.x; h[5] = hb.y; h[6] = hb.z; h[7] = hb.w;
        }
        float acc[8];
#pragma unroll
        for (int k = 0; k < 8; ++k) acc[k] = 0.f;

        int e = rowoff[ln];
        const int e1 = rowoff[ln + 1];
        const int nq = (e1 - e) >> 2;       // number of full quads
        if (nq > 0) {
            // prologue: issue quads 0 and 1
            uint4 u0, u1, u2, u3, v0q, v1q, v2q, v3q;
            {
                const int a0 = seB[e], a1 = seB[e + 1];
                const int a2 = seB[e + 2], a3 = seB[e + 3];
                u0 = featb4[a0 * 8 + l]; u1 = featb4[a1 * 8 + l];
                u2 = featb4[a2 * 8 + l]; u3 = featb4[a3 * 8 + l];
            }
            if (nq > 1) {
                const int a0 = seB[e + 4], a1 = seB[e + 5];
                const int a2 = seB[e + 6], a3 = seB[e + 7];
                v0q = featb4[a0 * 8 + l]; v1q = featb4[a1 * 8 + l];
                v2q = featb4[a2 * 8 + l]; v3q = featb4[a3 * 8 + l];
            }
            for (int q = 2; q < nq; ++q) {
                // issue quad q while quads q-2 (process now) and q-1 in flight
                const int eb = e + q * 4;
                const int a0 = seB[eb], a1 = seB[eb + 1];
                const int a2 = seB[eb + 2], a3 = seB[eb + 3];
                const uint4 w0 = featb4[a0 * 8 + l];
                const uint4 w1 = featb4[a1 * 8 + l];
                const uint4 w2 = featb4[a2 * 8 + l];
                const uint4 w3 = featb4[a3 * 8 + l];
                quad_proc(u0, u1, u2, u3, h, acc);
                u0 = v0q; u1 = v1q; u2 = v2q; u3 = v3q;
                v0q = w0; v1q = w1; v2q = w2; v3q = w3;
            }
            quad_proc(u0, u1, u2, u3, h, acc);
            if (nq > 1) quad_proc(v0q, v1q, v2q, v3q, h, acc);
            e += nq * 4;
        }
        for (; e < e1; ++e) {
            const uint4 u0 = featb4[seB[e] * 8 + l];
            float g0[8];
            float p0 = red8(cvt_dot(u0, h, g0));
#pragma unroll
            for (int k = 0; k < 8; ++k) acc[k] += g0[k] * p0;
        }
        neigh4[nidx * 16 + 2 * l]     = make_float4(acc[0], acc[1], acc[2], acc[3]);
        neigh4[nidx * 16 + 2 * l + 1] = make_float4(acc[4], acc[5], acc[6], acc[7]);
    }
}

// ---------- K4: in-place GEMM out[n,:] = out[n,:] @ W^T ----------
// 64-row tiles (was 128): LDS 34.8 KB (was 50.2) -> 4 blocks/CU (was 3),
// 1563 blocks (was 782) -> better CU utilization and tail. Thread owns
// 4 rows x 4 cols; nT float4 reads are conflict-free per 32-lane phase.
__global__ __launch_bounds__(256) void gemm_inplace(float* __restrict__ out,
                                                    const float* __restrict__ W) {
    __shared__ float WT[64][68];
    __shared__ float nT[64][68];
    const int t = threadIdx.x;

    const float4* W4 = (const float4*)W;
#pragma unroll
    for (int j = 0; j < 4; ++j) {
        const int f = t + j * 256;
        const int o = f >> 4;
        const int i4 = (f & 15) * 4;
        const float4 w = W4[f];
        WT[i4 + 0][o] = w.x;
        WT[i4 + 1][o] = w.y;
        WT[i4 + 2][o] = w.z;
        WT[i4 + 3][o] = w.w;
    }

    const int base = blockIdx.x * 64;
    const int rows = min(64, N_NODES - base);
    const float4* O4 = (const float4*)(out + (long)base * D);
#pragma unroll
    for (int j = 0; j < 4; ++j) {
        const int f = t + j * 256;
        const int r = f >> 4;
        const int i4 = (f & 15) * 4;
        if (r < rows) {
            const float4 x = O4[f];
            nT[i4 + 0][r] = x.x;
            nT[i4 + 1][r] = x.y;
            nT[i4 + 2][r] = x.z;
            nT[i4 + 3][r] = x.w;
        }
    }
    __syncthreads();

    const int c4 = (t & 15) * 4;
    const int r0 = (t >> 4) * 4;
    float acc[4][4];
#pragma unroll
    for (int r = 0; r < 4; ++r)
#pragma unroll
        for (int c = 0; c < 4; ++c) acc[r][c] = 0.f;

    for (int i = 0; i < 64; ++i) {
        const float4 w = *(const float4*)&WT[i][c4];
        const float4 ra = *(const float4*)&nT[i][r0];
        const float wv[4] = {w.x, w.y, w.z, w.w};
        const float rv[4] = {ra.x, ra.y, ra.z, ra.w};
#pragma unroll
        for (int r = 0; r < 4; ++r)
#pragma unroll
            for (int c = 0; c < 4; ++c) acc[r][c] += rv[r] * wv[c];
    }

#pragma unroll
    for (int r = 0; r < 4; ++r) {
        const int rr = r0 + r;
        if (rr < rows)
            *(float4*)&out[(long)(base + rr) * D + c4] =
                make_float4(acc[r][0], acc[r][1], acc[r][2], acc[r][3]);
    }
}

extern "C" void kernel_launch(void* const* d_in, const int* in_sizes, int n_in,
                              void* d_out, int out_size, void* d_ws, size_t ws_size,
                              hipStream_t stream) {
    const float* feat = (const float*)d_in[0];
    const int*   esrc = (const int*)d_in[1];
    const int*   edst = (const int*)d_in[2];
    const float* W    = (const float*)d_in[3];
    float* out = (float*)d_out;

    char* ws = (char*)d_ws;
    ushort_t* featb = (ushort_t*)(ws);                       // 12.8 MB
    int* slab = (int*)(ws + 12800000);                       // NB*CAP*4 = 9.61 MB
    int* gcur = (int*)(ws + 12800000 + (size_t)NB * CAP * 4);// 3.1 KB

    repack_init<<<(N_NODES * D / 16 + 255) / 256, 256, 0, stream>>>(feat, featb, gcur);
    partition<<<NPART, 1024, 0, stream>>>(esrc, edst, gcur, slab);
    fused_spmm<<<NB, 512, 0, stream>>>((const float4*)feat, (const uint4*)featb,
                                       slab, gcur, (float4*)out);
    gemm_inplace<<<(N_NODES + 63) / 64, 256, 0, stream>>>(out, W);
}